// Round 6
// baseline (1121.287 us; speedup 1.0000x reference)
//
#include <hip/hip_runtime.h>
#include <math.h>

#define N_NODES 16384
#define IN_DIM  512
#define HID_DIM 256
#define OUT_DIM 128
#define MAXDEG  128

typedef float f4v __attribute__((ext_vector_type(4)));

__device__ __forceinline__ float bf2f(unsigned short u) {
    return __uint_as_float(((unsigned int)u) << 16);
}
__device__ __forceinline__ unsigned short f2bf(float f) {
    unsigned int u = __float_as_uint(f);
    return (unsigned short)((u + 0x7FFFu + ((u >> 16) & 1u)) >> 16);
}

// ---------------------------------------------------------------------------
// 64x64 f32 GEMM tile (h1 = x @ W1, bf16 out). 256 threads, 4x4 micro-tile,
// K-chunk 16, As transposed [k][m] so fragments are ds_read_b128.
// ---------------------------------------------------------------------------
__device__ __forceinline__ void gemm_tile_bf16out(
    const float* __restrict__ Amat, const float* __restrict__ B,
    unsigned short* __restrict__ C, int K, int N, int m0, int n0,
    float (*As)[68], float (*Bs)[64]) {
    const int t  = threadIdx.x;
    const int tx = t & 15, ty = t >> 4;
    float acc[4][4] = {};
    for (int kt = 0; kt < K; kt += 16) {
        {
            const int m = t >> 2, k4 = (t & 3) * 4;
            const float4 v = *(const float4*)(Amat + (size_t)(m0 + m) * K + kt + k4);
            As[k4 + 0][m] = v.x; As[k4 + 1][m] = v.y;
            As[k4 + 2][m] = v.z; As[k4 + 3][m] = v.w;
        }
        {
            const int k = t >> 4, c4 = (t & 15) * 4;
            *(float4*)&Bs[k][c4] = *(const float4*)(B + (size_t)(kt + k) * N + n0 + c4);
        }
        __syncthreads();
        #pragma unroll
        for (int k = 0; k < 16; ++k) {
            const float4 a = *(const float4*)&As[k][ty * 4];
            const float4 b = *(const float4*)&Bs[k][tx * 4];
            const float av[4] = {a.x, a.y, a.z, a.w};
            const float bv[4] = {b.x, b.y, b.z, b.w};
            #pragma unroll
            for (int i = 0; i < 4; ++i)
                #pragma unroll
                for (int j = 0; j < 4; ++j)
                    acc[i][j] += av[i] * bv[j];
        }
        __syncthreads();
    }
    #pragma unroll
    for (int i = 0; i < 4; ++i) {
        const size_t off = (size_t)(m0 + ty * 4 + i) * N + n0 + tx * 4;
        ushort4 o;
        o.x = f2bf(acc[i][0]); o.y = f2bf(acc[i][1]);
        o.z = f2bf(acc[i][2]); o.w = f2bf(acc[i][3]);
        *(ushort4*)(C + off) = o;
    }
}

// ---------------------------------------------------------------------------
// Fused: every 5th block = one 64x64 tile of h1 = x @ W1 (interleaved with
// scan blocks so the HBM stream starts immediately — bid-first ordering
// regressed in round 4/5); other 4096 blocks scan the 1.07 GB adjacency
// (4 rows/block, wave/row, nontemporal loads, 2-chunk unroll).
// ---------------------------------------------------------------------------
__global__ __launch_bounds__(256) void scan_gemm_kernel(
    const float* __restrict__ A,
    int* __restrict__ adj, int* __restrict__ cnt, float* __restrict__ din,
    const float* __restrict__ X, const float* __restrict__ W1,
    unsigned short* __restrict__ H1) {
    __shared__ float As[16][68];
    __shared__ float Bs[16][64];
    const int bid = blockIdx.x;
    if (bid % 5 == 0) {
        const int g  = bid / 5;            // 0..1023
        const int n0 = (g & 3) * 64;
        const int m0 = (g >> 2) * 64;
        gemm_tile_bf16out(X, W1, H1, IN_DIM, HID_DIM, m0, n0, As, Bs);
        return;
    }
    const int s    = bid - bid / 5 - 1;    // 0..4095
    const int lane = threadIdx.x & 63;
    const int row  = s * 4 + (threadIdx.x >> 6);
    const f4v* arow = (const f4v*)(A + (size_t)row * N_NODES);
    const unsigned long long lt = (1ull << lane) - 1ull;
    int base = 0;
    for (int chunk = 0; chunk < N_NODES / 256; chunk += 2) {
        const f4v v0 = __builtin_nontemporal_load(&arow[chunk * 64 + lane]);
        const f4v v1 = __builtin_nontemporal_load(&arow[chunk * 64 + 64 + lane]);
        const float vv[8] = {v0.x, v0.y, v0.z, v0.w, v1.x, v1.y, v1.z, v1.w};
        #pragma unroll
        for (int h = 0; h < 2; ++h) {
            const int c0 = (chunk + h) * 256 + lane * 4;
            #pragma unroll
            for (int i = 0; i < 4; ++i) {
                const bool nz = vv[h * 4 + i] != 0.f;
                const unsigned long long m = __ballot(nz);
                if (nz) {
                    const int p = base + __popcll(m & lt);
                    if (p < MAXDEG) adj[row * MAXDEG + p] = c0 + i;
                }
                base += __popcll(m);
            }
        }
    }
    if (lane == 0) {
        cnt[row] = base < MAXDEG ? base : MAXDEG;
        din[row] = base > 0 ? 1.0f / sqrtf((float)base) : 0.0f;
    }
}

// ---------------------------------------------------------------------------
// agg1: 4 nodes/block (wave per node), bf16 gathers of h1, f32 accumulate,
// ELU + row L2-norm. Writes z1 f32 (output) AND z1b bf16 (for layer 2).
// High occupancy (4KB LDS) — gather latency hidden by ~32 waves/CU.
// ---------------------------------------------------------------------------
__global__ __launch_bounds__(256) void agg1_kernel(
    const unsigned short* __restrict__ h1, const int* __restrict__ adj,
    const int* __restrict__ cnt, const float* __restrict__ din,
    const float* __restrict__ b1, float* __restrict__ z1,
    unsigned short* __restrict__ z1b) {
    __shared__ int   s_adj[4][MAXDEG];
    __shared__ float s_dsc[4][MAXDEG];
    const int wid  = threadIdx.x >> 6;
    const int lane = threadIdx.x & 63;
    const int node = blockIdx.x * 4 + wid;
    const int n    = cnt[node];
    for (int e = lane; e < n; e += 64) {
        const int src = adj[node * MAXDEG + e];
        s_adj[wid][e] = src;
        s_dsc[wid][e] = din[src];
    }
    __syncthreads();
    const int c0 = lane * 4;
    float acc[4] = {};
    #define GATHER(idx_)                                                       \
        do {                                                                   \
            const int ei_ = (idx_);                                            \
            const ushort4 hv_ = *(const ushort4*)(                             \
                h1 + (size_t)s_adj[wid][ei_] * HID_DIM + c0);                  \
            const float w_ = s_dsc[wid][ei_];                                  \
            acc[0] += bf2f(hv_.x) * w_; acc[1] += bf2f(hv_.y) * w_;            \
            acc[2] += bf2f(hv_.z) * w_; acc[3] += bf2f(hv_.w) * w_;            \
        } while (0)
    int e = 0;
    for (; e + 8 <= n; e += 8) {
        #pragma unroll
        for (int uu = 0; uu < 8; ++uu) GATHER(e + uu);
    }
    for (; e < n; ++e) GATHER(e);
    #undef GATHER
    const float dn = din[node];
    float val[4];
    float ss = 0.f;
    #pragma unroll
    for (int u = 0; u < 4; ++u) {
        float v = acc[u] * dn + b1[c0 + u];
        v = v > 0.f ? v : expm1f(v);
        val[u] = v;
        ss += v * v;
    }
    #pragma unroll
    for (int off = 32; off > 0; off >>= 1) ss += __shfl_xor(ss, off, 64);
    const float inv = 1.0f / fmaxf(sqrtf(ss), 1e-12f);
    #pragma unroll
    for (int u = 0; u < 4; ++u) val[u] *= inv;
    *(float4*)(z1 + (size_t)node * HID_DIM + c0) =
        make_float4(val[0], val[1], val[2], val[3]);
    ushort4 ob;
    ob.x = f2bf(val[0]); ob.y = f2bf(val[1]);
    ob.z = f2bf(val[2]); ob.w = f2bf(val[3]);
    *(ushort4*)(z1b + (size_t)node * HID_DIM + c0) = ob;
}

// ---------------------------------------------------------------------------
// Fused layer 2 (linearity commute): agg and the linear map commute, so
//   z2[v] = l2norm( din[v] * (sum_u z1[u]*din[u]) @ W2 + b2 )
// — no h2 materialization, no separate GEMM. Per wave per node: gather bf16
// z1 rows -> s (lane j holds s[4j..4j+3]), scale din[v], then matvec via
// v_readlane broadcasts + LDS-staged W2 (bf16 pairs, k-major: lane j reads
// W2s[k*64+j] -> 2-way bank alias = free). 1024 thr / 16 waves, 72KB LDS
// -> 2 blocks/CU = 32 waves/CU (gather latency hidden).
// ---------------------------------------------------------------------------
__global__ __launch_bounds__(1024) void agg2_fused_kernel(
    const unsigned short* __restrict__ z1b, const int* __restrict__ adj,
    const int* __restrict__ cnt, const float* __restrict__ din,
    const float* __restrict__ W2, const float* __restrict__ b2,
    float* __restrict__ z2) {
    __shared__ unsigned int W2s[HID_DIM * 64];   // 64 KB
    __shared__ int s_adj[16][MAXDEG];            // 8 KB
    const int tid = threadIdx.x;
    for (int idx = tid; idx < HID_DIM * 64; idx += 1024) {
        const int k = idx >> 6, j = idx & 63;
        const float2 w = *(const float2*)(W2 + k * OUT_DIM + j * 2);
        W2s[idx] = ((unsigned int)f2bf(w.y) << 16) | (unsigned int)f2bf(w.x);
    }
    __syncthreads();
    const int wid  = tid >> 6;
    const int lane = tid & 63;
    const int c0   = lane * 4;
    for (int it = 0; it < 2; ++it) {
        const int node = (blockIdx.x * 16 + wid) * 2 + it;
        const int n    = cnt[node];
        for (int e = lane; e < n; e += 64)
            s_adj[wid][e] = adj[node * MAXDEG + e];
        // wave-local LDS staging: lockstep wave + compiler lgkmcnt ordering
        float acc[4] = {};
        #define GATHER(idx_)                                                   \
            do {                                                               \
                const int ei_  = (idx_);                                       \
                const int src_ = s_adj[wid][ei_];                              \
                const float w_ = din[src_];                                    \
                const ushort4 hv_ = *(const ushort4*)(                         \
                    z1b + (size_t)src_ * HID_DIM + c0);                        \
                acc[0] += bf2f(hv_.x) * w_; acc[1] += bf2f(hv_.y) * w_;        \
                acc[2] += bf2f(hv_.z) * w_; acc[3] += bf2f(hv_.w) * w_;        \
            } while (0)
        int e = 0;
        for (; e + 8 <= n; e += 8) {
            #pragma unroll
            for (int uu = 0; uu < 8; ++uu) GATHER(e + uu);
        }
        for (; e < n; ++e) GATHER(e);
        #undef GATHER
        const float dn = din[node];
        #pragma unroll
        for (int u = 0; u < 4; ++u) acc[u] *= dn;
        // matvec: lane j computes cols 2j, 2j+1 of s @ W2
        float h0 = 0.f, h1v = 0.f;
        #pragma unroll
        for (int k = 0; k < HID_DIM; ++k) {
            const float sk = __shfl(acc[k & 3], k >> 2, 64);  // v_readlane
            const unsigned int w = W2s[k * 64 + lane];
            h0  += sk * __uint_as_float(w << 16);
            h1v += sk * __uint_as_float(w & 0xffff0000u);
        }
        const float v0 = h0  + b2[lane * 2];
        const float v1 = h1v + b2[lane * 2 + 1];
        float ss = v0 * v0 + v1 * v1;
        #pragma unroll
        for (int off = 32; off > 0; off >>= 1) ss += __shfl_xor(ss, off, 64);
        const float inv = 1.0f / fmaxf(sqrtf(ss), 1e-12f);
        *(float2*)(z2 + (size_t)node * OUT_DIM + lane * 2) =
            make_float2(v0 * inv, v1 * inv);
    }
}

// ---------------------------------------------------------------------------
extern "C" void kernel_launch(void* const* d_in, const int* in_sizes, int n_in,
                              void* d_out, int out_size, void* d_ws, size_t ws_size,
                              hipStream_t stream) {
    const float* x  = (const float*)d_in[0];
    const float* A  = (const float*)d_in[1];
    const float* W1 = (const float*)d_in[2];
    const float* b1 = (const float*)d_in[3];
    const float* W2 = (const float*)d_in[4];
    const float* b2 = (const float*)d_in[5];

    float* out = (float*)d_out;
    float* z2  = out;                                   // 16384 x 128
    float* z1  = out + (size_t)N_NODES * OUT_DIM;       // 16384 x 256

    char* p = (char*)d_ws;
    int*   adj = (int*)p;            p += (size_t)N_NODES * MAXDEG * sizeof(int);
    int*   cnt = (int*)p;            p += (size_t)N_NODES * sizeof(int);
    float* din = (float*)p;          p += (size_t)N_NODES * sizeof(float);
    unsigned short* h1 = (unsigned short*)p;
    p += (size_t)N_NODES * HID_DIM * sizeof(unsigned short);
    unsigned short* z1b = (unsigned short*)p;

    // 1) [A-scan || h1 = bf16(x @ W1)] fused, bid%5 interleave
    scan_gemm_kernel<<<5120, 256, 0, stream>>>(A, adj, cnt, din, x, W1, h1);

    // 2) z1 = l2norm(elu(agg(h1*din)*din + b1)) -> f32 out + bf16 ws
    agg1_kernel<<<N_NODES / 4, 256, 0, stream>>>(
        h1, adj, cnt, din, b1, z1, z1b);

    // 3) z2 = l2norm((agg(z1b*din)*din) @ W2 + b2)  [linearity commute]
    agg2_fused_kernel<<<512, 1024, 0, stream>>>(
        z1b, adj, cnt, din, W2, b2, z2);
}

// Round 7
// 270.273 us; speedup vs baseline: 4.1487x; 4.1487x over previous
//
#include <hip/hip_runtime.h>
#include <math.h>

#define N_NODES 16384
#define IN_DIM  512
#define HID_DIM 256
#define OUT_DIM 128
#define MAXDEG  128

typedef float f4v __attribute__((ext_vector_type(4)));

__device__ __forceinline__ float bf2f(unsigned short u) {
    return __uint_as_float(((unsigned int)u) << 16);
}
__device__ __forceinline__ unsigned short f2bf(float f) {
    unsigned int u = __float_as_uint(f);
    return (unsigned short)((u + 0x7FFFu + ((u >> 16) & 1u)) >> 16);
}

// ---------------------------------------------------------------------------
// 64x64 f32 GEMM tile, bf16 out. 256 threads, 4x4 micro-tile, K-chunk 16,
// As transposed [k][m] so fragments are ds_read_b128.
// ---------------------------------------------------------------------------
__device__ __forceinline__ void gemm_tile_bf16out(
    const float* __restrict__ Amat, const float* __restrict__ B,
    unsigned short* __restrict__ C, int K, int N, int m0, int n0,
    float (*As)[68], float (*Bs)[64]) {
    const int t  = threadIdx.x;
    const int tx = t & 15, ty = t >> 4;
    float acc[4][4] = {};
    for (int kt = 0; kt < K; kt += 16) {
        {
            const int m = t >> 2, k4 = (t & 3) * 4;
            const float4 v = *(const float4*)(Amat + (size_t)(m0 + m) * K + kt + k4);
            As[k4 + 0][m] = v.x; As[k4 + 1][m] = v.y;
            As[k4 + 2][m] = v.z; As[k4 + 3][m] = v.w;
        }
        {
            const int k = t >> 4, c4 = (t & 15) * 4;
            *(float4*)&Bs[k][c4] = *(const float4*)(B + (size_t)(kt + k) * N + n0 + c4);
        }
        __syncthreads();
        #pragma unroll
        for (int k = 0; k < 16; ++k) {
            const float4 a = *(const float4*)&As[k][ty * 4];
            const float4 b = *(const float4*)&Bs[k][tx * 4];
            const float av[4] = {a.x, a.y, a.z, a.w};
            const float bv[4] = {b.x, b.y, b.z, b.w};
            #pragma unroll
            for (int i = 0; i < 4; ++i)
                #pragma unroll
                for (int j = 0; j < 4; ++j)
                    acc[i][j] += av[i] * bv[j];
        }
        __syncthreads();
    }
    #pragma unroll
    for (int i = 0; i < 4; ++i) {
        const size_t off = (size_t)(m0 + ty * 4 + i) * N + n0 + tx * 4;
        ushort4 o;
        o.x = f2bf(acc[i][0]); o.y = f2bf(acc[i][1]);
        o.z = f2bf(acc[i][2]); o.w = f2bf(acc[i][3]);
        *(ushort4*)(C + off) = o;
    }
}

// ---------------------------------------------------------------------------
// Fused: every 5th block = one 64x64 tile of h1 = x @ W1 (interleaved with
// scan blocks so the HBM stream starts immediately); other 4096 blocks scan
// the 1.07 GB adjacency (4 rows/block, wave/row, nontemporal loads, 4-chunk
// unroll for deeper memory-level parallelism) building adj lists + deg^-1/2.
// ---------------------------------------------------------------------------
__global__ __launch_bounds__(256) void scan_gemm_kernel(
    const float* __restrict__ A,
    int* __restrict__ adj, int* __restrict__ cnt, float* __restrict__ din,
    const float* __restrict__ X, const float* __restrict__ W1,
    unsigned short* __restrict__ H1) {
    __shared__ float As[16][68];
    __shared__ float Bs[16][64];
    const int bid = blockIdx.x;
    if (bid % 5 == 0) {
        const int g  = bid / 5;            // 0..1023
        const int n0 = (g & 3) * 64;
        const int m0 = (g >> 2) * 64;
        gemm_tile_bf16out(X, W1, H1, IN_DIM, HID_DIM, m0, n0, As, Bs);
        return;
    }
    const int s    = bid - bid / 5 - 1;    // 0..4095
    const int lane = threadIdx.x & 63;
    const int row  = s * 4 + (threadIdx.x >> 6);
    const f4v* arow = (const f4v*)(A + (size_t)row * N_NODES);
    const unsigned long long lt = (1ull << lane) - 1ull;
    int base = 0;
    for (int chunk = 0; chunk < N_NODES / 256; chunk += 4) {
        const f4v v0 = __builtin_nontemporal_load(&arow[(chunk + 0) * 64 + lane]);
        const f4v v1 = __builtin_nontemporal_load(&arow[(chunk + 1) * 64 + lane]);
        const f4v v2 = __builtin_nontemporal_load(&arow[(chunk + 2) * 64 + lane]);
        const f4v v3 = __builtin_nontemporal_load(&arow[(chunk + 3) * 64 + lane]);
        const float vv[16] = {v0.x, v0.y, v0.z, v0.w, v1.x, v1.y, v1.z, v1.w,
                              v2.x, v2.y, v2.z, v2.w, v3.x, v3.y, v3.z, v3.w};
        #pragma unroll
        for (int h = 0; h < 4; ++h) {
            const int c0 = (chunk + h) * 256 + lane * 4;
            #pragma unroll
            for (int i = 0; i < 4; ++i) {
                const bool nz = vv[h * 4 + i] != 0.f;
                const unsigned long long m = __ballot(nz);
                if (nz) {
                    const int p = base + __popcll(m & lt);
                    if (p < MAXDEG) adj[row * MAXDEG + p] = c0 + i;
                }
                base += __popcll(m);
            }
        }
    }
    if (lane == 0) {
        cnt[row] = base < MAXDEG ? base : MAXDEG;
        din[row] = base > 0 ? 1.0f / sqrtf((float)base) : 0.0f;
    }
}

// ---------------------------------------------------------------------------
// Standalone GEMM (h2 = z1 @ W2 -> bf16).
// ---------------------------------------------------------------------------
__global__ __launch_bounds__(256) void gemm_kernel(
    const float* __restrict__ Amat, const float* __restrict__ B,
    unsigned short* __restrict__ C, int K, int N) {
    __shared__ float As[16][68];
    __shared__ float Bs[16][64];
    gemm_tile_bf16out(Amat, B, C, K, N, blockIdx.y * 64, blockIdx.x * 64,
                      As, Bs);
}

// ---------------------------------------------------------------------------
// Aggregation: 4 nodes per 256-thread block (one wave per node), bf16 row
// gathers, unroll-8 edge loop, f32 accumulate + (ELU) + row L2-norm, f32 out.
// out[v] = l2norm( [elu]( din[v] * sum_e h[adj_e]*din[adj_e] + b ) )
// Small LDS (8 KB) -> full occupancy; gather latency hidden by many waves.
// ---------------------------------------------------------------------------
template<int D, int VPT, bool DO_ELU>
__global__ __launch_bounds__(256) void agg_kernel(
    const unsigned short* __restrict__ h, const int* __restrict__ adj,
    const int* __restrict__ cnt, const float* __restrict__ din,
    const float* __restrict__ bias, float* __restrict__ out) {
    __shared__ int   s_adj[4][MAXDEG];
    __shared__ float s_dsc[4][MAXDEG];
    const int wid  = threadIdx.x >> 6;
    const int lane = threadIdx.x & 63;
    const int node = blockIdx.x * 4 + wid;
    const int n    = cnt[node];
    for (int e = lane; e < n; e += 64) {
        const int src = adj[node * MAXDEG + e];
        s_adj[wid][e] = src;
        s_dsc[wid][e] = din[src];
    }
    __syncthreads();
    const int c0 = lane * VPT;
    float acc[VPT] = {};
    #define GATHER(idx_)                                                       \
        do {                                                                   \
            const int ei_ = (idx_);                                            \
            const float w_ = s_dsc[wid][ei_];                                  \
            const unsigned short* hp_ =                                        \
                h + (size_t)s_adj[wid][ei_] * D + c0;                          \
            if (VPT == 4) {                                                    \
                const ushort4 hv_ = *(const ushort4*)hp_;                      \
                acc[0] += bf2f(hv_.x) * w_; acc[1] += bf2f(hv_.y) * w_;        \
                acc[2] += bf2f(hv_.z) * w_; acc[3 % VPT] += bf2f(hv_.w) * w_;  \
            } else {                                                           \
                const ushort2 hv_ = *(const ushort2*)hp_;                      \
                acc[0] += bf2f(hv_.x) * w_; acc[1 % VPT] += bf2f(hv_.y) * w_;  \
            }                                                                  \
        } while (0)
    int e = 0;
    for (; e + 8 <= n; e += 8) {
        #pragma unroll
        for (int uu = 0; uu < 8; ++uu) GATHER(e + uu);
    }
    for (; e < n; ++e) GATHER(e);
    #undef GATHER
    const float dn = din[node];
    float val[VPT];
    float ss = 0.f;
    #pragma unroll
    for (int u = 0; u < VPT; ++u) {
        float v = acc[u] * dn + bias[c0 + u];
        if (DO_ELU) v = v > 0.f ? v : expm1f(v);
        val[u] = v;
        ss += v * v;
    }
    #pragma unroll
    for (int off = 32; off > 0; off >>= 1) ss += __shfl_xor(ss, off, 64);
    const float inv = 1.0f / fmaxf(sqrtf(ss), 1e-12f);
    #pragma unroll
    for (int u = 0; u < VPT; ++u) val[u] *= inv;
    if (VPT == 4)
        *(float4*)(out + (size_t)node * D + c0) =
            make_float4(val[0], val[1], val[2], val[3 % VPT]);
    else
        *(float2*)(out + (size_t)node * D + c0) = make_float2(val[0], val[1 % VPT]);
}

// ---------------------------------------------------------------------------
extern "C" void kernel_launch(void* const* d_in, const int* in_sizes, int n_in,
                              void* d_out, int out_size, void* d_ws, size_t ws_size,
                              hipStream_t stream) {
    const float* x  = (const float*)d_in[0];
    const float* A  = (const float*)d_in[1];
    const float* W1 = (const float*)d_in[2];
    const float* b1 = (const float*)d_in[3];
    const float* W2 = (const float*)d_in[4];
    const float* b2 = (const float*)d_in[5];

    float* out = (float*)d_out;
    float* z2  = out;                                   // 16384 x 128
    float* z1  = out + (size_t)N_NODES * OUT_DIM;       // 16384 x 256

    char* p = (char*)d_ws;
    int*   adj = (int*)p;            p += (size_t)N_NODES * MAXDEG * sizeof(int);
    int*   cnt = (int*)p;            p += (size_t)N_NODES * sizeof(int);
    float* din = (float*)p;          p += (size_t)N_NODES * sizeof(float);
    unsigned short* h1 = (unsigned short*)p;
    p += (size_t)N_NODES * HID_DIM * sizeof(unsigned short);
    unsigned short* h2 = (unsigned short*)p;

    // 1) [A-scan || h1 = bf16(x @ W1)] fused, bid%5 interleave
    scan_gemm_kernel<<<5120, 256, 0, stream>>>(A, adj, cnt, din, x, W1, h1);

    // 2) z1 = l2norm(elu(agg(h1*din)*din + b1)) -> f32
    agg_kernel<HID_DIM, 4, true><<<N_NODES / 4, 256, 0, stream>>>(
        h1, adj, cnt, din, b1, z1);

    // 3) h2 = bf16(z1 @ W2)
    gemm_kernel<<<dim3(OUT_DIM / 64, N_NODES / 64), 256, 0, stream>>>(
        z1, W2, h2, HID_DIM, OUT_DIM);

    // 4) z2 = l2norm(agg(h2*din)*din + b2) -> f32
    agg_kernel<OUT_DIM, 2, false><<<N_NODES / 4, 256, 0, stream>>>(
        h2, adj, cnt, din, b2, z2);
}

// Round 8
// 262.639 us; speedup vs baseline: 4.2693x; 1.0291x over previous
//
#include <hip/hip_runtime.h>
#include <math.h>

#define N_NODES 16384
#define IN_DIM  512
#define HID_DIM 256
#define OUT_DIM 128
#define MAXDEG  128

typedef float f4v __attribute__((ext_vector_type(4)));
typedef float f32x4 __attribute__((ext_vector_type(4)));
typedef short bf16x8 __attribute__((ext_vector_type(8)));

__device__ __forceinline__ float bf2f(unsigned short u) {
    return __uint_as_float(((unsigned int)u) << 16);
}
__device__ __forceinline__ unsigned short f2bf(float f) {
    unsigned int u = __float_as_uint(f);
    return (unsigned short)((u + 0x7FFFu + ((u >> 16) & 1u)) >> 16);
}

// ---------------------------------------------------------------------------
// 64x64 f32 GEMM tile (h1 = x @ W1, bf16 out). 256 threads, 4x4 micro-tile,
// K-chunk 16, As transposed [k][m] so fragments are ds_read_b128.
// ---------------------------------------------------------------------------
__device__ __forceinline__ void gemm_tile_bf16out(
    const float* __restrict__ Amat, const float* __restrict__ B,
    unsigned short* __restrict__ C, int K, int N, int m0, int n0,
    float (*As)[68], float (*Bs)[64]) {
    const int t  = threadIdx.x;
    const int tx = t & 15, ty = t >> 4;
    float acc[4][4] = {};
    for (int kt = 0; kt < K; kt += 16) {
        {
            const int m = t >> 2, k4 = (t & 3) * 4;
            const float4 v = *(const float4*)(Amat + (size_t)(m0 + m) * K + kt + k4);
            As[k4 + 0][m] = v.x; As[k4 + 1][m] = v.y;
            As[k4 + 2][m] = v.z; As[k4 + 3][m] = v.w;
        }
        {
            const int k = t >> 4, c4 = (t & 15) * 4;
            *(float4*)&Bs[k][c4] = *(const float4*)(B + (size_t)(kt + k) * N + n0 + c4);
        }
        __syncthreads();
        #pragma unroll
        for (int k = 0; k < 16; ++k) {
            const float4 a = *(const float4*)&As[k][ty * 4];
            const float4 b = *(const float4*)&Bs[k][tx * 4];
            const float av[4] = {a.x, a.y, a.z, a.w};
            const float bv[4] = {b.x, b.y, b.z, b.w};
            #pragma unroll
            for (int i = 0; i < 4; ++i)
                #pragma unroll
                for (int j = 0; j < 4; ++j)
                    acc[i][j] += av[i] * bv[j];
        }
        __syncthreads();
    }
    #pragma unroll
    for (int i = 0; i < 4; ++i) {
        const size_t off = (size_t)(m0 + ty * 4 + i) * N + n0 + tx * 4;
        ushort4 o;
        o.x = f2bf(acc[i][0]); o.y = f2bf(acc[i][1]);
        o.z = f2bf(acc[i][2]); o.w = f2bf(acc[i][3]);
        *(ushort4*)(C + off) = o;
    }
}

// ---------------------------------------------------------------------------
// Fused: every 5th block = one 64x64 tile of h1 = x @ W1; other 4096 blocks
// scan the 1.07 GB adjacency (4 rows/block, wave/row, nontemporal loads,
// 2-chunk unroll — the 4-chunk variant regressed in round 7).
// ---------------------------------------------------------------------------
__global__ __launch_bounds__(256) void scan_gemm_kernel(
    const float* __restrict__ A,
    int* __restrict__ adj, int* __restrict__ cnt, float* __restrict__ din,
    const float* __restrict__ X, const float* __restrict__ W1,
    unsigned short* __restrict__ H1) {
    __shared__ float As[16][68];
    __shared__ float Bs[16][64];
    const int bid = blockIdx.x;
    if (bid % 5 == 0) {
        const int g  = bid / 5;            // 0..1023
        const int n0 = (g & 3) * 64;
        const int m0 = (g >> 2) * 64;
        gemm_tile_bf16out(X, W1, H1, IN_DIM, HID_DIM, m0, n0, As, Bs);
        return;
    }
    const int s    = bid - bid / 5 - 1;    // 0..4095
    const int lane = threadIdx.x & 63;
    const int row  = s * 4 + (threadIdx.x >> 6);
    const f4v* arow = (const f4v*)(A + (size_t)row * N_NODES);
    const unsigned long long lt = (1ull << lane) - 1ull;
    int base = 0;
    for (int chunk = 0; chunk < N_NODES / 256; chunk += 2) {
        const f4v v0 = __builtin_nontemporal_load(&arow[chunk * 64 + lane]);
        const f4v v1 = __builtin_nontemporal_load(&arow[chunk * 64 + 64 + lane]);
        const float vv[8] = {v0.x, v0.y, v0.z, v0.w, v1.x, v1.y, v1.z, v1.w};
        #pragma unroll
        for (int h = 0; h < 2; ++h) {
            const int c0 = (chunk + h) * 256 + lane * 4;
            #pragma unroll
            for (int i = 0; i < 4; ++i) {
                const bool nz = vv[h * 4 + i] != 0.f;
                const unsigned long long m = __ballot(nz);
                if (nz) {
                    const int p = base + __popcll(m & lt);
                    if (p < MAXDEG) adj[row * MAXDEG + p] = c0 + i;
                }
                base += __popcll(m);
            }
        }
    }
    if (lane == 0) {
        cnt[row] = base < MAXDEG ? base : MAXDEG;
        din[row] = base > 0 ? 1.0f / sqrtf((float)base) : 0.0f;
    }
}

// ---------------------------------------------------------------------------
// agg1: 4 nodes/block (wave per node), bf16 gathers of h1, f32 accumulate,
// ELU + row L2-norm. Writes z1 f32 (output) AND z1b bf16 (layer-2 input).
// Small LDS -> full occupancy; gather latency hidden by many waves.
// ---------------------------------------------------------------------------
__global__ __launch_bounds__(256) void agg1_kernel(
    const unsigned short* __restrict__ h1, const int* __restrict__ adj,
    const int* __restrict__ cnt, const float* __restrict__ din,
    const float* __restrict__ b1, float* __restrict__ z1,
    unsigned short* __restrict__ z1b) {
    __shared__ int   s_adj[4][MAXDEG];
    __shared__ float s_dsc[4][MAXDEG];
    const int wid  = threadIdx.x >> 6;
    const int lane = threadIdx.x & 63;
    const int node = blockIdx.x * 4 + wid;
    const int n    = cnt[node];
    for (int e = lane; e < n; e += 64) {
        const int src = adj[node * MAXDEG + e];
        s_adj[wid][e] = src;
        s_dsc[wid][e] = din[src];
    }
    __syncthreads();
    const int c0 = lane * 4;
    float acc[4] = {};
    #define GATHER(idx_)                                                       \
        do {                                                                   \
            const int ei_ = (idx_);                                            \
            const ushort4 hv_ = *(const ushort4*)(                             \
                h1 + (size_t)s_adj[wid][ei_] * HID_DIM + c0);                  \
            const float w_ = s_dsc[wid][ei_];                                  \
            acc[0] += bf2f(hv_.x) * w_; acc[1] += bf2f(hv_.y) * w_;            \
            acc[2] += bf2f(hv_.z) * w_; acc[3] += bf2f(hv_.w) * w_;            \
        } while (0)
    int e = 0;
    for (; e + 8 <= n; e += 8) {
        #pragma unroll
        for (int uu = 0; uu < 8; ++uu) GATHER(e + uu);
    }
    for (; e < n; ++e) GATHER(e);
    #undef GATHER
    const float dn = din[node];
    float val[4];
    float ss = 0.f;
    #pragma unroll
    for (int u = 0; u < 4; ++u) {
        float v = acc[u] * dn + b1[c0 + u];
        v = v > 0.f ? v : expm1f(v);
        val[u] = v;
        ss += v * v;
    }
    #pragma unroll
    for (int off = 32; off > 0; off >>= 1) ss += __shfl_xor(ss, off, 64);
    const float inv = 1.0f / fmaxf(sqrtf(ss), 1e-12f);
    #pragma unroll
    for (int u = 0; u < 4; ++u) val[u] *= inv;
    *(float4*)(z1 + (size_t)node * HID_DIM + c0) =
        make_float4(val[0], val[1], val[2], val[3]);
    ushort4 ob;
    ob.x = f2bf(val[0]); ob.y = f2bf(val[1]);
    ob.z = f2bf(val[2]); ob.w = f2bf(val[3]);
    *(ushort4*)(z1b + (size_t)node * HID_DIM + c0) = ob;
}

// ---------------------------------------------------------------------------
// gemm2 via MFMA: h2 = bf16(z1b @ W2). 256 blocks x 256 thr (4 waves).
// Wave w: rows m0+16w..+15, all 128 cols. A-frags read direct from global
// (16B/lane, z1b L2-hot). W2 staged transposed in LDS [128][264] bf16
// (row stride 528B = 33x16B: b128-aligned; lane&15 stride 132 dwords ->
// bank 4*(l&15)%32: 2-way alias = free).
// Frag layouts (m89-verified family): A row=l&15, k=(l>>4)*8+j;
// B col=l&15, k=(l>>4)*8+j; C/D col=l&15, row=(l>>4)*4+reg.
// ---------------------------------------------------------------------------
__global__ __launch_bounds__(256) void gemm2_mfma_kernel(
    const unsigned short* __restrict__ Z, const float* __restrict__ W2,
    unsigned short* __restrict__ H2) {
    __shared__ unsigned short W2t[OUT_DIM][HID_DIM + 8];   // 66 KB
    const int tid = threadIdx.x;
    for (int idx = tid; idx < OUT_DIM * HID_DIM / 2; idx += 256) {
        const int n = idx >> 7, kk = (idx & 127) * 2;
        W2t[n][kk]     = f2bf(W2[(size_t)kk * OUT_DIM + n]);
        W2t[n][kk + 1] = f2bf(W2[(size_t)(kk + 1) * OUT_DIM + n]);
    }
    __syncthreads();
    const int wave = tid >> 6, lane = tid & 63;
    const int m0   = blockIdx.x * 64 + wave * 16;
    const int arow = m0 + (lane & 15);
    const int koff = (lane >> 4) * 8;
    bf16x8 afrag[8];
    #pragma unroll
    for (int ks = 0; ks < 8; ++ks)
        afrag[ks] = *(const bf16x8*)(Z + (size_t)arow * HID_DIM + ks * 32 + koff);
    const int orow = m0 + (lane >> 4) * 4;
    #pragma unroll
    for (int nt = 0; nt < 8; ++nt) {
        f32x4 acc = {0.f, 0.f, 0.f, 0.f};
        const unsigned short* wcol = &W2t[nt * 16 + (lane & 15)][koff];
        #pragma unroll
        for (int ks = 0; ks < 8; ++ks) {
            const bf16x8 bfrag = *(const bf16x8*)(wcol + ks * 32);
            acc = __builtin_amdgcn_mfma_f32_16x16x32_bf16(afrag[ks], bfrag, acc,
                                                          0, 0, 0);
        }
        #pragma unroll
        for (int r = 0; r < 4; ++r)
            H2[(size_t)(orow + r) * OUT_DIM + nt * 16 + (lane & 15)] =
                f2bf(acc[r]);
    }
}

// ---------------------------------------------------------------------------
// agg2: 4 nodes/block (wave per node), bf16 gathers of h2, f32 accumulate,
// bias + row L2-norm, f32 out.
// ---------------------------------------------------------------------------
__global__ __launch_bounds__(256) void agg2_kernel(
    const unsigned short* __restrict__ h, const int* __restrict__ adj,
    const int* __restrict__ cnt, const float* __restrict__ din,
    const float* __restrict__ bias, float* __restrict__ out) {
    __shared__ int   s_adj[4][MAXDEG];
    __shared__ float s_dsc[4][MAXDEG];
    const int wid  = threadIdx.x >> 6;
    const int lane = threadIdx.x & 63;
    const int node = blockIdx.x * 4 + wid;
    const int n    = cnt[node];
    for (int e = lane; e < n; e += 64) {
        const int src = adj[node * MAXDEG + e];
        s_adj[wid][e] = src;
        s_dsc[wid][e] = din[src];
    }
    __syncthreads();
    const int c0 = lane * 2;
    float acc[2] = {};
    #define GATHER(idx_)                                                       \
        do {                                                                   \
            const int ei_ = (idx_);                                            \
            const ushort2 hv_ = *(const ushort2*)(                             \
                h + (size_t)s_adj[wid][ei_] * OUT_DIM + c0);                   \
            const float w_ = s_dsc[wid][ei_];                                  \
            acc[0] += bf2f(hv_.x) * w_; acc[1] += bf2f(hv_.y) * w_;            \
        } while (0)
    int e = 0;
    for (; e + 8 <= n; e += 8) {
        #pragma unroll
        for (int uu = 0; uu < 8; ++uu) GATHER(e + uu);
    }
    for (; e < n; ++e) GATHER(e);
    #undef GATHER
    const float dn = din[node];
    const float v0 = acc[0] * dn + bias[c0];
    const float v1 = acc[1] * dn + bias[c0 + 1];
    float ss = v0 * v0 + v1 * v1;
    #pragma unroll
    for (int off = 32; off > 0; off >>= 1) ss += __shfl_xor(ss, off, 64);
    const float inv = 1.0f / fmaxf(sqrtf(ss), 1e-12f);
    *(float2*)(out + (size_t)node * OUT_DIM + c0) =
        make_float2(v0 * inv, v1 * inv);
}

// ---------------------------------------------------------------------------
extern "C" void kernel_launch(void* const* d_in, const int* in_sizes, int n_in,
                              void* d_out, int out_size, void* d_ws, size_t ws_size,
                              hipStream_t stream) {
    const float* x  = (const float*)d_in[0];
    const float* A  = (const float*)d_in[1];
    const float* W1 = (const float*)d_in[2];
    const float* b1 = (const float*)d_in[3];
    const float* W2 = (const float*)d_in[4];
    const float* b2 = (const float*)d_in[5];

    float* out = (float*)d_out;
    float* z2  = out;                                   // 16384 x 128
    float* z1  = out + (size_t)N_NODES * OUT_DIM;       // 16384 x 256

    char* p = (char*)d_ws;
    int*   adj = (int*)p;            p += (size_t)N_NODES * MAXDEG * sizeof(int);
    int*   cnt = (int*)p;            p += (size_t)N_NODES * sizeof(int);
    float* din = (float*)p;          p += (size_t)N_NODES * sizeof(float);
    unsigned short* h1 = (unsigned short*)p;
    p += (size_t)N_NODES * HID_DIM * sizeof(unsigned short);
    unsigned short* z1b = (unsigned short*)p;
    p += (size_t)N_NODES * HID_DIM * sizeof(unsigned short);
    unsigned short* h2 = (unsigned short*)p;

    // 1) [A-scan || h1 = bf16(x @ W1)] fused, bid%5 interleave
    scan_gemm_kernel<<<5120, 256, 0, stream>>>(A, adj, cnt, din, x, W1, h1);

    // 2) z1 = l2norm(elu(agg(h1*din)*din + b1)) -> f32 out + bf16 ws
    agg1_kernel<<<N_NODES / 4, 256, 0, stream>>>(
        h1, adj, cnt, din, b1, z1, z1b);

    // 3) h2 = bf16(z1b @ W2) via MFMA
    gemm2_mfma_kernel<<<N_NODES / 64, 256, 0, stream>>>(z1b, W2, h2);

    // 4) z2 = l2norm(agg(h2*din)*din + b2) -> f32
    agg2_kernel<<<N_NODES / 4, 256, 0, stream>>>(h2, adj, cnt, din, b2, z2);
}